// Round 12
// baseline (76.667 us; speedup 1.0000x reference)
//
#include <hip/hip_runtime.h>

typedef _Float16 v8h __attribute__((ext_vector_type(8)));
typedef float v16f __attribute__((ext_vector_type(16)));

#define BB 8
#define NN 8192
#define MM 8192
#define SPLITM 8          // j-chunks per batch
#define CPTS 1024         // xyz2 points per chunk
#define JTC 32            // 32-point j-tiles per chunk
#define TPB 256           // 4 waves
#define NI 4              // i-tiles (B-frags) per wave -> 4 independent MFMA chains

// Homogeneous K=16 encoding (k = (lane>>5)*8 + reg):
//  k=0..2 : A = yhat_c          B = -2*xhat_c
//  k=3,4  : A = (y2)_hi,(y2)_lo B = 1, 1
//  k=5,6  : A = 1, 1            B = (x2)_hi,(x2)_lo
//  k=7..15: B = 0  =>  A's k>=8 slots are DON'T-CARE -> A stored compressed;
//  all lanes read the khalf=0 frag (lane-pair same-addr broadcast, conflict-free).

__device__ __forceinline__ float min3f(float a, float b, float c) {
    return fminf(fminf(a, b), c);  // -> v_min3_f32
}

__global__ __launch_bounds__(TPB, 4) void chamfer_min_mfma(const float* __restrict__ xyz1,
                                                           const float* __restrict__ xyz2,
                                                           float* __restrict__ pmins) {
    __shared__ v8h aLds[CPTS];  // 16 KB compressed A-frags

    // grid = 1024: bid = b*128 + jchunk*16 + ig
    int ig     = blockIdx.x & 15;
    int jchunk = (blockIdx.x >> 4) & 7;
    int b      = blockIdx.x >> 7;
    int t = threadIdx.x;
    int wid = t >> 6;
    int lane = t & 63;
    int laneq = lane & 31;
    int half = lane >> 5;

    // ---- fused A pack: convert this chunk's 1024 xyz2 points, 4/thread ----
    const float* srcA = xyz2 + ((size_t)b * MM + (size_t)jchunk * CPTS) * 3;
#pragma unroll
    for (int k = 0; k < CPTS / TPB; ++k) {
        int p = k * TPB + t;
        float x = srcA[p * 3 + 0], y = srcA[p * 3 + 1], z = srcA[p * 3 + 2];
        _Float16 h0 = (_Float16)x, h1 = (_Float16)y, h2 = (_Float16)z;
        float y0 = (float)h0, y1 = (float)h1, y2v = (float)h2;
        float s = fmaf(y0, y0, fmaf(y1, y1, y2v * y2v));
        _Float16 shi = (_Float16)s;
        _Float16 slo = (_Float16)(s - (float)shi);
        v8h v = {h0, h1, h2, shi, slo, (_Float16)1.0f, (_Float16)1.0f, (_Float16)0.0f};
        aLds[p] = v;
    }

    // ---- fused B pack: this wave's four i-tiles (khalf=1 lanes stay zero) ----
    int it0 = (ig * 4 + wid) * NI;
    v8h bf[NI];
#pragma unroll
    for (int tt = 0; tt < NI; ++tt) {
        int i = (it0 + tt) * 32 + laneq;
        const float* p = xyz1 + ((size_t)b * NN + i) * 3;
        _Float16 h0 = (_Float16)p[0], h1 = (_Float16)p[1], h2 = (_Float16)p[2];
        float x0 = (float)h0, x1 = (float)h1, x2v = (float)h2;
        float s = fmaf(x0, x0, fmaf(x1, x1, x2v * x2v));
        _Float16 shi = (_Float16)s;
        _Float16 slo = (_Float16)(s - (float)shi);
        v8h v = {};
        if (half == 0) {
            v[0] = (_Float16)(-2.0f * x0);
            v[1] = (_Float16)(-2.0f * x1);
            v[2] = (_Float16)(-2.0f * x2v);
            v[3] = (_Float16)1.0f; v[4] = (_Float16)1.0f;
            v[5] = shi; v[6] = slo;
        }
        bf[tt] = v;
    }

    __syncthreads();

    // ---- main loop: 1 broadcast ds_read + 4 independent MFMAs + min3 trees ----
    // 4 back-to-back MFMAs cover result latency before c[0] is consumed.
    const v16f zc = {};
    float mg[NI][4];
#pragma unroll
    for (int tt = 0; tt < NI; ++tt)
#pragma unroll
        for (int g = 0; g < 4; ++g) mg[tt][g] = 1e30f;

#pragma unroll 1
    for (int jt = 0; jt < JTC; ++jt) {
        v8h a = aLds[jt * 32 + laneq];
        v16f c[NI];
#pragma unroll
        for (int tt = 0; tt < NI; ++tt)
            c[tt] = __builtin_amdgcn_mfma_f32_32x32x16_f16(a, bf[tt], zc, 0, 0, 0);
#pragma unroll
        for (int tt = 0; tt < NI; ++tt)
#pragma unroll
            for (int g = 0; g < 4; ++g) {
                int r = 4 * g;
                mg[tt][g] = min3f(min3f(c[tt][r], c[tt][r + 1], c[tt][r + 2]),
                                  c[tt][r + 3], mg[tt][g]);
            }
    }

    // ---- epilogue: merge groups + row-halves; one dword per lane per tile-pair ----
#pragma unroll
    for (int tt = 0; tt < NI; tt += 2) {
        float m0 = fminf(min3f(mg[tt][0], mg[tt][1], mg[tt][2]), mg[tt][3]);
        float m1 = fminf(min3f(mg[tt + 1][0], mg[tt + 1][1], mg[tt + 1][2]), mg[tt + 1][3]);
        m0 = fminf(m0, __shfl_xor(m0, 32));
        m1 = fminf(m1, __shfl_xor(m1, 32));
        int i = (it0 + tt + half) * 32 + laneq;  // halves write tiles tt / tt+1
        pmins[(size_t)jchunk * (BB * NN) + (size_t)b * NN + i] = half ? m1 : m0;
    }
}

__global__ __launch_bounds__(256) void chamfer_reduce(const float* __restrict__ pmins,
                                                      float* __restrict__ out) {
    int i = blockIdx.x * 256 + threadIdx.x;  // grid 256 blocks
    float m = pmins[i];
#pragma unroll
    for (int sp = 1; sp < SPLITM; ++sp)
        m = fminf(m, pmins[(size_t)sp * (BB * NN) + i]);
    float s = m;
#pragma unroll
    for (int off = 32; off > 0; off >>= 1) s += __shfl_down(s, off);
    __shared__ float ls[4];
    int lane = threadIdx.x & 63, wv = threadIdx.x >> 6;
    if (lane == 0) ls[wv] = s;
    __syncthreads();
    if (threadIdx.x == 0) {
        float tt = (ls[0] + ls[1]) + (ls[2] + ls[3]);
        atomicAdd(out, tt * (1.0f / (float)(BB * NN)));
    }
}

extern "C" void kernel_launch(void* const* d_in, const int* in_sizes, int n_in,
                              void* d_out, int out_size, void* d_ws, size_t ws_size,
                              hipStream_t stream) {
    const float* xyz1 = (const float*)d_in[0];
    const float* xyz2 = (const float*)d_in[1];
    float* out = (float*)d_out;
    float* pmins = (float*)d_ws;

    hipMemsetAsync(out, 0, sizeof(float), stream);
    chamfer_min_mfma<<<BB * SPLITM * 16, TPB, 0, stream>>>(xyz1, xyz2, pmins);
    chamfer_reduce<<<(BB * NN) / 256, 256, 0, stream>>>(pmins, out);
}

// Round 13
// 76.103 us; speedup vs baseline: 1.0074x; 1.0074x over previous
//
#include <hip/hip_runtime.h>

typedef _Float16 v8h __attribute__((ext_vector_type(8)));
typedef float v16f __attribute__((ext_vector_type(16)));

#define BB 8
#define NN 8192
#define MM 8192
#define SPLITM 8          // j-chunks per batch
#define CPTS 1024         // xyz2 points per chunk
#define JTC 32            // 32-point j-tiles per chunk
#define TPB 256           // 4 waves
#define NI 2              // i-tiles (B-frags) per wave

// Homogeneous K=16 encoding (k = (lane>>5)*8 + reg):
//  k=0..2 : A = yhat_c          B = -2*xhat_c
//  k=3,4  : A = (y2)_hi,(y2)_lo B = 1, 1
//  k=5,6  : A = 1, 1            B = (x2)_hi,(x2)_lo
//  k=7..15: B = 0  =>  A's k>=8 slots are DON'T-CARE -> A stored compressed;
//  all lanes read the khalf=0 frag (lane-pair same-addr broadcast, conflict-free).

__device__ __forceinline__ float min3f(float a, float b, float c) {
    return fminf(fminf(a, b), c);  // -> v_min3_f32
}

__global__ __launch_bounds__(TPB, 4) void chamfer_min_mfma(const float* __restrict__ xyz1,
                                                           const float* __restrict__ xyz2,
                                                           float* __restrict__ pmins) {
    __shared__ v8h aLds[CPTS];  // 16 KB compressed A-frags

    // grid = 2048: bid = b*256 + jchunk*32 + ig
    int ig     = blockIdx.x & 31;
    int jchunk = (blockIdx.x >> 5) & 7;
    int b      = blockIdx.x >> 8;
    int t = threadIdx.x;
    int wid = t >> 6;
    int lane = t & 63;
    int laneq = lane & 31;
    int half = lane >> 5;

    // ---- fused A pack: convert this chunk's 1024 xyz2 points, 4/thread ----
    const float* srcA = xyz2 + ((size_t)b * MM + (size_t)jchunk * CPTS) * 3;
#pragma unroll
    for (int k = 0; k < CPTS / TPB; ++k) {
        int p = k * TPB + t;
        float x = srcA[p * 3 + 0], y = srcA[p * 3 + 1], z = srcA[p * 3 + 2];
        _Float16 h0 = (_Float16)x, h1 = (_Float16)y, h2 = (_Float16)z;
        float y0 = (float)h0, y1 = (float)h1, y2v = (float)h2;
        float s = fmaf(y0, y0, fmaf(y1, y1, y2v * y2v));
        _Float16 shi = (_Float16)s;
        _Float16 slo = (_Float16)(s - (float)shi);
        v8h v = {h0, h1, h2, shi, slo, (_Float16)1.0f, (_Float16)1.0f, (_Float16)0.0f};
        aLds[p] = v;
    }

    // ---- fused B pack: this wave's two i-tiles (khalf=1 lanes stay zero) ----
    int it0 = (ig * 4 + wid) * NI;
    v8h bf[NI];
#pragma unroll
    for (int tt = 0; tt < NI; ++tt) {
        int i = (it0 + tt) * 32 + laneq;
        const float* p = xyz1 + ((size_t)b * NN + i) * 3;
        _Float16 h0 = (_Float16)p[0], h1 = (_Float16)p[1], h2 = (_Float16)p[2];
        float x0 = (float)h0, x1 = (float)h1, x2v = (float)h2;
        float s = fmaf(x0, x0, fmaf(x1, x1, x2v * x2v));
        _Float16 shi = (_Float16)s;
        _Float16 slo = (_Float16)(s - (float)shi);
        v8h v = {};
        if (half == 0) {
            v[0] = (_Float16)(-2.0f * x0);
            v[1] = (_Float16)(-2.0f * x1);
            v[2] = (_Float16)(-2.0f * x2v);
            v[3] = (_Float16)1.0f; v[4] = (_Float16)1.0f;
            v[5] = shi; v[6] = slo;
        }
        bf[tt] = v;
    }

    __syncthreads();

    // ---- main loop, de-convoyed:
    //  (a) per-wave jt rotation: waves start 8 tiles apart -> LDS/MFMA phases stagger
    //  (b) register software-pipeline: a(jt+1) ds_read issued while jt computes
    const v16f zc = {};
    float mg[NI][4];
#pragma unroll
    for (int tt = 0; tt < NI; ++tt)
#pragma unroll
        for (int g = 0; g < 4; ++g) mg[tt][g] = 1e30f;

    int jt0 = wid * 8;
    v8h a_next = aLds[jt0 * 32 + laneq];
#pragma unroll 1
    for (int s = 0; s < JTC; ++s) {
        v8h a = a_next;
        int jn = ((s + 1) & (JTC - 1)) * 32;       // wrap: harmless reload of jt0
        int jtn = (jn + jt0 * 32) & (CPTS - 1);
        a_next = aLds[jtn + laneq];
        v16f c[NI];
#pragma unroll
        for (int tt = 0; tt < NI; ++tt)
            c[tt] = __builtin_amdgcn_mfma_f32_32x32x16_f16(a, bf[tt], zc, 0, 0, 0);
#pragma unroll
        for (int tt = 0; tt < NI; ++tt)
#pragma unroll
            for (int g = 0; g < 4; ++g) {
                int r = 4 * g;
                mg[tt][g] = min3f(min3f(c[tt][r], c[tt][r + 1], c[tt][r + 2]),
                                  c[tt][r + 3], mg[tt][g]);
            }
    }

    // ---- epilogue: merge groups + row-halves; one dword per lane per tile-pair ----
    float m0 = fminf(min3f(mg[0][0], mg[0][1], mg[0][2]), mg[0][3]);
    float m1 = fminf(min3f(mg[1][0], mg[1][1], mg[1][2]), mg[1][3]);
    m0 = fminf(m0, __shfl_xor(m0, 32));
    m1 = fminf(m1, __shfl_xor(m1, 32));
    int i = (it0 + half) * 32 + laneq;
    pmins[(size_t)jchunk * (BB * NN) + (size_t)b * NN + i] = half ? m1 : m0;
}

__global__ __launch_bounds__(256) void chamfer_reduce(const float* __restrict__ pmins,
                                                      float* __restrict__ out) {
    int i = blockIdx.x * 256 + threadIdx.x;  // grid 256 blocks
    float m = pmins[i];
#pragma unroll
    for (int sp = 1; sp < SPLITM; ++sp)
        m = fminf(m, pmins[(size_t)sp * (BB * NN) + i]);
    float s = m;
#pragma unroll
    for (int off = 32; off > 0; off >>= 1) s += __shfl_down(s, off);
    __shared__ float ls[4];
    int lane = threadIdx.x & 63, wv = threadIdx.x >> 6;
    if (lane == 0) ls[wv] = s;
    __syncthreads();
    if (threadIdx.x == 0) {
        float tt = (ls[0] + ls[1]) + (ls[2] + ls[3]);
        atomicAdd(out, tt * (1.0f / (float)(BB * NN)));
    }
}

extern "C" void kernel_launch(void* const* d_in, const int* in_sizes, int n_in,
                              void* d_out, int out_size, void* d_ws, size_t ws_size,
                              hipStream_t stream) {
    const float* xyz1 = (const float*)d_in[0];
    const float* xyz2 = (const float*)d_in[1];
    float* out = (float*)d_out;
    float* pmins = (float*)d_ws;

    hipMemsetAsync(out, 0, sizeof(float), stream);
    chamfer_min_mfma<<<BB * SPLITM * 32, TPB, 0, stream>>>(xyz1, xyz2, pmins);
    chamfer_reduce<<<(BB * NN) / 256, 256, 0, stream>>>(pmins, out);
}